// Round 9
// baseline (166.308 us; speedup 1.0000x reference)
//
#include <hip/hip_runtime.h>
#include <stdint.h>

typedef __attribute__((ext_vector_type(8))) short short8;
typedef __attribute__((ext_vector_type(4))) float f32x4;
typedef unsigned short u16;
typedef unsigned int u32;

#define NSIG   16
#define NPER   4096
#define DIN    256
#define DMODEL 1024
#define NB     16
#define NL     4096
#define LP1    4097
#define LDK32  40   // bf16 row stride: 80B rows -> 16B-aligned b128 reads

// ---------------------------------------------------------------------------
// Fused: f32 -> reg prefetch -> bf16 LDS (BK=32) -> MFMA (SWAPPED operands:
// outcol on the reg axis -> f32x4 epilogue) -> vectorized scatter epilogue
// + attn_keep/CLS tail.  grid = 4096 x 256.  LDS = 20.0 KB.
// GEMM core identical to round-7 (proven); only operand order + epilogue
// indexing changed.  Note: __builtin_nontemporal_store needs ext_vector
// types (f32x4), not HIP_vector_type float4.
// ---------------------------------------------------------------------------
__global__ __launch_bounds__(256, 4)
void enc_fused(const float* __restrict__ emb,     // [65536][256] f32
               const int* __restrict__ eidx,
               const int* __restrict__ pos,
               const int* __restrict__ sid,
               const int* __restrict__ mod_,
               const int* __restrict__ role,
               const unsigned char* __restrict__ pmask,
               const float* __restrict__ Wp,      // [16][1024][256] f32
               const float* __restrict__ bp,
               const float* __restrict__ cls,
               const float* __restrict__ pos_t,
               const float* __restrict__ id_t,
               const float* __restrict__ mod_t,
               const float* __restrict__ role_t,
               float* __restrict__ out)
{
    __shared__ u16 Ab[128 * LDK32];   // 10.0 KB
    __shared__ u16 Bb[128 * LDK32];   // 10.0 KB

    // XCD-chunked bijective swizzle (4096 % 8 == 0)
    const int bid = blockIdx.x;
    const int lg = (bid & 7) * 512 + (bid >> 3);
    const int rowBase = (lg >> 3) * 128;
    const int colBase = (lg & 7) * 128;
    const int s = rowBase >> 12;

    const int t = threadIdx.x;
    const int lane = t & 63;
    const int w = t >> 6;
    const int wr = w >> 1, wc = w & 1;
    const int l4 = lane >> 4;

    f32x4 acc[4][4] = {};   // acc[m][n]: token = m*16+(lane&15), col = n*16+l4*4+j

    // staging map: thread t -> rows r0+p*32, float col c4f (float4-wide)
    const int r0 = t >> 3;            // 0..31
    const int c4f = (t & 7) * 4;      // 0,4,..,28

    const float* Ag = emb + (size_t)rowBase * DIN;
    const float* Bg = Wp + ((size_t)s * DMODEL + colBase) * DIN;

    // ---- prologue: k-tile 0 into registers ----
    float4 rA[4], rB[4];
    #pragma unroll
    for (int p = 0; p < 4; ++p) {
        const int r = p * 32 + r0;
        rA[p] = *(const float4*)(Ag + (size_t)r * DIN + c4f);
        rB[p] = *(const float4*)(Bg + (size_t)r * DIN + c4f);
    }

    for (int kk = 0; kk < DIN; kk += 32) {
        // ---- pack current regs -> LDS (proven pack math) ----
        #pragma unroll
        for (int p = 0; p < 4; ++p) {
            const int r = p * 32 + r0;
            const float4 va = rA[p];
            const float4 vb = rB[p];
            uint2 pa, pb;
            pa.x = (__builtin_bit_cast(u32, va.x) >> 16) | (__builtin_bit_cast(u32, va.y) & 0xFFFF0000u);
            pa.y = (__builtin_bit_cast(u32, va.z) >> 16) | (__builtin_bit_cast(u32, va.w) & 0xFFFF0000u);
            pb.x = (__builtin_bit_cast(u32, vb.x) >> 16) | (__builtin_bit_cast(u32, vb.y) & 0xFFFF0000u);
            pb.y = (__builtin_bit_cast(u32, vb.z) >> 16) | (__builtin_bit_cast(u32, vb.w) & 0xFFFF0000u);
            *(uint2*)&Ab[r * LDK32 + c4f] = pa;
            *(uint2*)&Bb[r * LDK32 + c4f] = pb;
        }
        __syncthreads();

        // ---- issue next k-tile loads (hide under MFMA) ----
        if (kk + 32 < DIN) {
            #pragma unroll
            for (int p = 0; p < 4; ++p) {
                const int r = p * 32 + r0;
                rA[p] = *(const float4*)(Ag + (size_t)r * DIN + kk + 32 + c4f);
                rB[p] = *(const float4*)(Bg + (size_t)r * DIN + kk + 32 + c4f);
            }
        }

        // ---- MFMA, operands SWAPPED: token on lane axis, outcol on reg axis
        {
            const int ko = l4 * 8;
            short8 af[4], bf[4];
            #pragma unroll
            for (int m = 0; m < 4; ++m)
                af[m] = *(const short8*)&Ab[(wr * 64 + m * 16 + (lane & 15)) * LDK32 + ko];
            #pragma unroll
            for (int n = 0; n < 4; ++n)
                bf[n] = *(const short8*)&Bb[(wc * 64 + n * 16 + (lane & 15)) * LDK32 + ko];
            #pragma unroll
            for (int m = 0; m < 4; ++m) {
                #pragma unroll
                for (int n = 0; n < 4; ++n)
                    acc[m][n] = __builtin_amdgcn_mfma_f32_16x16x32_bf16(
                        bf[n], af[m], acc[m][n], 0, 0, 0);
            }
        }
        __syncthreads();
    }

    // ---- epilogue: f32x4 bias/gathers/stores, one metadata chain per m ----
    const int colQ = colBase + wc * 64 + l4 * 4;   // + n*16 -> 16B-aligned
    f32x4 bpv[4];
    #pragma unroll
    for (int n = 0; n < 4; ++n)
        bpv[n] = *(const f32x4*)&bp[s * DMODEL + colQ + n * 16];

    int idxm[4], pvm[4], svm[4], mvm[4], rvm[4], pmm[4];
    #pragma unroll
    for (int m = 0; m < 4; ++m)
        idxm[m] = eidx[rowBase + wr * 64 + m * 16 + (lane & 15)];
    #pragma unroll
    for (int m = 0; m < 4; ++m) {
        pvm[m] = pos[idxm[m]];
        svm[m] = sid[idxm[m]];
        mvm[m] = mod_[idxm[m]];
        rvm[m] = role[idxm[m]];
        pmm[m] = pmask[idxm[m]];
    }

    #pragma unroll
    for (int m = 0; m < 4; ++m) {
        const int idx = idxm[m];
        const size_t orow =
            ((size_t)(idx >> 12) * LP1 + 1 + (size_t)(idx & 4095)) * DMODEL;
        const float* pr = pos_t + (size_t)pvm[m] * DMODEL;
        const float* ir = id_t + (size_t)svm[m] * DMODEL;
        const float* mr = mod_t + (size_t)mvm[m] * DMODEL;
        const float* rr = role_t + (size_t)rvm[m] * DMODEL;
        const bool pm = pmm[m] != 0;
        #pragma unroll
        for (int n = 0; n < 4; ++n) {
            const int col = colQ + n * 16;
            const f32x4 pv = *(const f32x4*)&pr[col];
            const f32x4 iv = *(const f32x4*)&ir[col];
            const f32x4 mv = *(const f32x4*)&mr[col];
            const f32x4 rv = *(const f32x4*)&rr[col];
            f32x4 v = acc[m][n] + bpv[n] + pv + iv + mv + rv;
            if (pm) v = (f32x4){0.0f, 0.0f, 0.0f, 0.0f};
            __builtin_nontemporal_store(v, (f32x4*)&out[orow + col]);
        }
    }

    // ---- aux tail (proven): attn_keep + CLS rows ----
    const int gid = bid * 256 + t;
    if (gid < NB * LP1) {
        const size_t OUT_TOK = (size_t)NB * LP1 * DMODEL;
        const int b = gid / LP1;
        const int r = gid - b * LP1;
        float keep = 1.0f;
        if (r > 0) keep = pmask[b * NL + r - 1] ? 0.0f : 1.0f;
        out[OUT_TOK + gid] = keep;
    }
    if (gid < NB * DMODEL) {
        const int b = gid >> 10;
        const int e = gid & (DMODEL - 1);
        out[(size_t)b * LP1 * DMODEL + e] = cls[e];
    }
}

extern "C" void kernel_launch(void* const* d_in, const int* in_sizes, int n_in,
                              void* d_out, int out_size, void* d_ws, size_t ws_size,
                              hipStream_t stream)
{
    (void)in_sizes; (void)n_in; (void)out_size; (void)d_ws; (void)ws_size;
    const float*         emb    = (const float*)d_in[0];
    const int*           eidx   = (const int*)d_in[1];
    const int*           pos    = (const int*)d_in[2];
    const int*           sid    = (const int*)d_in[3];
    const int*           mod_   = (const int*)d_in[4];
    const int*           role   = (const int*)d_in[5];
    const unsigned char* pmask  = (const unsigned char*)d_in[6];
    const float*         Wp     = (const float*)d_in[7];
    const float*         bp     = (const float*)d_in[8];
    const float*         cls    = (const float*)d_in[9];
    const float*         pos_t  = (const float*)d_in[10];
    const float*         id_t   = (const float*)d_in[11];
    const float*         mod_t  = (const float*)d_in[12];
    const float*         role_t = (const float*)d_in[13];
    float* out = (float*)d_out;

    enc_fused<<<4096, 256, 0, stream>>>(emb, eidx, pos, sid, mod_, role, pmask,
                                        Wp, bp, cls, pos_t, id_t, mod_t, role_t, out);
}

// Round 10
// 130.168 us; speedup vs baseline: 1.2776x; 1.2776x over previous
//
#include <hip/hip_runtime.h>
#include <stdint.h>

typedef __attribute__((ext_vector_type(8))) short short8;
typedef __attribute__((ext_vector_type(4))) float f32x4;
typedef unsigned short u16;
typedef unsigned int u32;

#define NSIG   16
#define NPER   4096
#define DIN    256
#define DMODEL 1024
#define NB     16
#define NL     4096
#define LP1    4097
#define LDK32  40   // bf16 row stride: 80B rows -> 16B-aligned b128 reads

// ---------------------------------------------------------------------------
// Round-7 base (130 us, proven): f32 -> reg prefetch -> bf16 LDS (BK=32) ->
// MFMA -> scatter epilogue + aux tail.  ONLY change vs r7: epilogue metadata
// chains batched (hoist 16 eidx loads, then 4 parallel meta chains per m)
// to overlap the idx->meta->table latency chain 4-wide.
// Access pattern / addresses / values identical to r7 (FETCH/WRITE tripwire:
// expect ~164/318 MB; r9's swapped layout gave 206/399 and regressed).
// ---------------------------------------------------------------------------
__global__ __launch_bounds__(256, 4)
void enc_fused(const float* __restrict__ emb,     // [65536][256] f32
               const int* __restrict__ eidx,
               const int* __restrict__ pos,
               const int* __restrict__ sid,
               const int* __restrict__ mod_,
               const int* __restrict__ role,
               const unsigned char* __restrict__ pmask,
               const float* __restrict__ Wp,      // [16][1024][256] f32
               const float* __restrict__ bp,
               const float* __restrict__ cls,
               const float* __restrict__ pos_t,
               const float* __restrict__ id_t,
               const float* __restrict__ mod_t,
               const float* __restrict__ role_t,
               float* __restrict__ out)
{
    __shared__ u16 Ab[128 * LDK32];   // 10.0 KB
    __shared__ u16 Bb[128 * LDK32];   // 10.0 KB

    // XCD-chunked bijective swizzle (4096 % 8 == 0)
    const int bid = blockIdx.x;
    const int lg = (bid & 7) * 512 + (bid >> 3);
    const int rowBase = (lg >> 3) * 128;
    const int colBase = (lg & 7) * 128;
    const int s = rowBase >> 12;

    const int t = threadIdx.x;
    const int lane = t & 63;
    const int w = t >> 6;
    const int wr = w >> 1, wc = w & 1;
    const int l4 = lane >> 4;

    f32x4 acc[4][4] = {};

    // staging map: thread t -> rows r0+p*32, float col c4f (float4-wide)
    const int r0 = t >> 3;            // 0..31
    const int c4f = (t & 7) * 4;      // 0,4,..,28

    const float* Ag = emb + (size_t)rowBase * DIN;
    const float* Bg = Wp + ((size_t)s * DMODEL + colBase) * DIN;

    // ---- prologue: k-tile 0 into registers ----
    float4 rA[4], rB[4];
    #pragma unroll
    for (int p = 0; p < 4; ++p) {
        const int r = p * 32 + r0;
        rA[p] = *(const float4*)(Ag + (size_t)r * DIN + c4f);
        rB[p] = *(const float4*)(Bg + (size_t)r * DIN + c4f);
    }

    for (int kk = 0; kk < DIN; kk += 32) {
        // ---- pack current regs -> LDS (proven pack math) ----
        #pragma unroll
        for (int p = 0; p < 4; ++p) {
            const int r = p * 32 + r0;
            const float4 va = rA[p];
            const float4 vb = rB[p];
            uint2 pa, pb;
            pa.x = (__builtin_bit_cast(u32, va.x) >> 16) | (__builtin_bit_cast(u32, va.y) & 0xFFFF0000u);
            pa.y = (__builtin_bit_cast(u32, va.z) >> 16) | (__builtin_bit_cast(u32, va.w) & 0xFFFF0000u);
            pb.x = (__builtin_bit_cast(u32, vb.x) >> 16) | (__builtin_bit_cast(u32, vb.y) & 0xFFFF0000u);
            pb.y = (__builtin_bit_cast(u32, vb.z) >> 16) | (__builtin_bit_cast(u32, vb.w) & 0xFFFF0000u);
            *(uint2*)&Ab[r * LDK32 + c4f] = pa;
            *(uint2*)&Bb[r * LDK32 + c4f] = pb;
        }
        __syncthreads();

        // ---- issue next k-tile loads (hide under MFMA) ----
        if (kk + 32 < DIN) {
            #pragma unroll
            for (int p = 0; p < 4; ++p) {
                const int r = p * 32 + r0;
                rA[p] = *(const float4*)(Ag + (size_t)r * DIN + kk + 32 + c4f);
                rB[p] = *(const float4*)(Bg + (size_t)r * DIN + kk + 32 + c4f);
            }
        }

        // ---- MFMA: one K=32 step (proven fragment pattern, r7 operand order)
        {
            const int ko = l4 * 8;
            short8 af[4], bf[4];
            #pragma unroll
            for (int m = 0; m < 4; ++m)
                af[m] = *(const short8*)&Ab[(wr * 64 + m * 16 + (lane & 15)) * LDK32 + ko];
            #pragma unroll
            for (int n = 0; n < 4; ++n)
                bf[n] = *(const short8*)&Bb[(wc * 64 + n * 16 + (lane & 15)) * LDK32 + ko];
            #pragma unroll
            for (int m = 0; m < 4; ++m) {
                #pragma unroll
                for (int n = 0; n < 4; ++n)
                    acc[m][n] = __builtin_amdgcn_mfma_f32_16x16x32_bf16(
                        af[m], bf[n], acc[m][n], 0, 0, 0);
            }
        }
        __syncthreads();
    }

    // ---- epilogue (r7 addresses/values; chains batched 4-wide) ----
    const int cb = colBase + wc * 64 + (lane & 15);
    float bpv[4];
    #pragma unroll
    for (int n = 0; n < 4; ++n) bpv[n] = bp[s * DMODEL + cb + n * 16];

    // hoist all 16 token indices (independent, issue together)
    int idxv[16];
    #pragma unroll
    for (int q = 0; q < 16; ++q)
        idxv[q] = eidx[rowBase + wr * 64 + (q >> 2) * 16 + l4 * 4 + (q & 3)];

    #pragma unroll
    for (int m = 0; m < 4; ++m) {
        // batch the 4 j-chains' metadata loads (issue 20 loads together)
        int pv4[4], sv4[4], mv4[4], rv4[4], pm4[4];
        #pragma unroll
        for (int j = 0; j < 4; ++j) {
            const int idx = idxv[m * 4 + j];
            pv4[j] = pos[idx];
            sv4[j] = sid[idx];
            mv4[j] = mod_[idx];
            rv4[j] = role[idx];
            pm4[j] = pmask[idx];
        }
        #pragma unroll
        for (int j = 0; j < 4; ++j) {
            const int idx = idxv[m * 4 + j];
            const size_t orow =
                ((size_t)(idx >> 12) * LP1 + 1 + (size_t)(idx & 4095)) * DMODEL;
            const float* pr = pos_t + (size_t)pv4[j] * DMODEL;
            const float* ir = id_t + (size_t)sv4[j] * DMODEL;
            const float* mr = mod_t + (size_t)mv4[j] * DMODEL;
            const float* rr = role_t + (size_t)rv4[j] * DMODEL;
            const bool pm = pm4[j] != 0;
            #pragma unroll
            for (int n = 0; n < 4; ++n) {
                const int col = cb + n * 16;
                float v = acc[m][n][j] + bpv[n]
                        + pr[col] + ir[col] + mr[col] + rr[col];
                v = pm ? 0.0f : v;
                __builtin_nontemporal_store(v, &out[orow + col]);
            }
        }
    }

    // ---- aux tail (proven): attn_keep + CLS rows ----
    const int gid = bid * 256 + t;
    if (gid < NB * LP1) {
        const size_t OUT_TOK = (size_t)NB * LP1 * DMODEL;
        const int b = gid / LP1;
        const int r = gid - b * LP1;
        float keep = 1.0f;
        if (r > 0) keep = pmask[b * NL + r - 1] ? 0.0f : 1.0f;
        out[OUT_TOK + gid] = keep;
    }
    if (gid < NB * DMODEL) {
        const int b = gid >> 10;
        const int e = gid & (DMODEL - 1);
        out[(size_t)b * LP1 * DMODEL + e] = cls[e];
    }
}

extern "C" void kernel_launch(void* const* d_in, const int* in_sizes, int n_in,
                              void* d_out, int out_size, void* d_ws, size_t ws_size,
                              hipStream_t stream)
{
    (void)in_sizes; (void)n_in; (void)out_size; (void)d_ws; (void)ws_size;
    const float*         emb    = (const float*)d_in[0];
    const int*           eidx   = (const int*)d_in[1];
    const int*           pos    = (const int*)d_in[2];
    const int*           sid    = (const int*)d_in[3];
    const int*           mod_   = (const int*)d_in[4];
    const int*           role   = (const int*)d_in[5];
    const unsigned char* pmask  = (const unsigned char*)d_in[6];
    const float*         Wp     = (const float*)d_in[7];
    const float*         bp     = (const float*)d_in[8];
    const float*         cls    = (const float*)d_in[9];
    const float*         pos_t  = (const float*)d_in[10];
    const float*         id_t   = (const float*)d_in[11];
    const float*         mod_t  = (const float*)d_in[12];
    const float*         role_t = (const float*)d_in[13];
    float* out = (float*)d_out;

    enc_fused<<<4096, 256, 0, stream>>>(emb, eidx, pos, sid, mod_, role, pmask,
                                        Wp, bp, cls, pos_t, id_t, mod_t, role_t, out);
}